// Round 1
// 93.969 us; speedup vs baseline: 1.0505x; 1.0505x over previous
//
#include <hip/hip_runtime.h>

#define B 8
#define C 4
#define H 384
#define W 384
#define HW (H * W)
#define CHW (C * H * W)
#define NTOT (B * CHW)        // 4,718,592
#define BIG2 589824           // 768^2, reference's BIG cap squared
#define TPI 144               // tiles per image (12x12 of 32x32)
#define NBLK (B * TPI)        // 1152
#define LOG2E 1.44269504088896340736f

// Full-width 64-bit scan (slow/rare paths only). min over set bits p of
// (p - lx)^2 ; 999 sentinel if empty side. lx in [16,48).
__device__ __forceinline__ int nearest2(unsigned long long m, int lx, int shl) {
    unsigned long long right = m >> lx;
    int dR = right ? (int)__builtin_ctzll(right) : 999;
    unsigned long long leftb = m << shl;            // shl = 63 - lx
    int dL = leftb ? (int)__builtin_clzll(leftb) : 999;
    int d = min(dR, dL);
    return d * d;
}

// Windowed 32-bit scan. right: bit0 = own pixel, bit k = dx=+k (reach 31).
// left: bit31 = own pixel, bit 30 = dx=-1, ... (reach >= 16). Sentinel 999
// keeps the ">289 -> ring" exactness invariant identical to nearest2's.
__device__ __forceinline__ int scan32(unsigned int right, unsigned int left, int add) {
    int dR = right ? __builtin_ctz(right) : 999;
    int dL = left ? __builtin_clz(left) : 999;
    int d = min(dR, dL);
    return d * d + add;
}

// Exact Chebyshev-ring global-memory scan (essentially never taken).
__device__ __attribute__((noinline))
int ring_fallback(const int* __restrict__ tg, int xa, int ya, int c, int best) {
    for (int d = 17; d * d < best; ++d) {
        int xlo = xa - d, xhi = xa + d, ylo = ya - d, yhi = ya + d;
        for (int xx = max(xlo, 0); xx <= min(xhi, W - 1); ++xx) {
            int ddx = xx - xa;
            int bb = ddx * ddx + d * d;
            if (bb < best) {
                if (ylo >= 0 && tg[ylo * W + xx] == c) best = bb;
                if (yhi < H && tg[yhi * W + xx] == c) best = min(best, bb);
            }
        }
        for (int yy = max(ylo + 1, 0); yy <= min(yhi - 1, H - 1); ++yy) {
            int ddy = yy - ya;
            int bb = ddy * ddy + d * d;
            if (bb < best) {
                if (xlo >= 0 && tg[yy * W + xlo] == c) best = bb;
                if (xhi < W && tg[yy * W + xhi] == c) best = min(best, bb);
            }
        }
    }
    return best;
}

// One 256-thread block per 32x32 tile. Thread owns 4 CONSECUTIVE COLUMNS of
// one row (y = tid>>3, x = (tid&7)*4) so the 4 pixels share all class/level
// masks: 8 broadcast b128 LDS reads/thread (was 32), float4 output loads
// (was 16 scalar), and windowed 32-bit scans (constant-shift alignbit
// extracts of one u64>>xq) replace 64-bit scans in the hot loop.
__global__ __launch_bounds__(256)
void dist_loss_kernel(const float* __restrict__ outputs,
                      const int* __restrict__ targets,
                      float* __restrict__ parts) {
    __shared__ unsigned long long rowsm[64][4];   // raw class masks (y halo 16)
    __shared__ unsigned long long big[32 * 18];   // [y][c][lvl0..3], 144B/row pad
    __shared__ float sred[4][9];

    int bid = blockIdx.x;
    int bx = bid % 12, by = (bid / 12) % 12, b = bid / TPI;
    int x0 = bx * 32, y0 = by * 32;
    int tid = threadIdx.x, lane = tid & 63, wv = tid >> 6;
    const int* tg = targets + b * HW;

    // ---- stage 64 rows of class bitmasks via ballot ----
    bool edge = (bx == 0) | (bx == 11) | (by == 0) | (by == 11);
    if (!edge) {
        const int* tp = tg + (y0 - 16 + wv) * W + (x0 - 16 + lane);
        for (int i = 0; i < 16; ++i) {
            int r = i * 4 + wv;
            int tv = tp[i * 4 * W];
            unsigned long long m0 = __ballot(tv == 0);
            unsigned long long m1 = __ballot(tv == 1);
            unsigned long long m2 = __ballot(tv == 2);
            unsigned long long m3 = __ballot(tv == 3);
            if (lane == 0) {
                rowsm[r][0] = m0; rowsm[r][1] = m1;
                rowsm[r][2] = m2; rowsm[r][3] = m3;
            }
        }
    } else {
        for (int i = 0; i < 16; ++i) {
            int r = i * 4 + wv;
            int ya = y0 - 16 + r, xa = x0 - 16 + lane;
            bool valid = (ya >= 0) & (ya < H) & (xa >= 0) & (xa < W);
            int yc = min(max(ya, 0), H - 1), xc = min(max(xa, 0), W - 1);
            int tv = tg[yc * W + xc];
            unsigned long long m0 = __ballot(valid && tv == 0);
            unsigned long long m1 = __ballot(valid && tv == 1);
            unsigned long long m2 = __ballot(valid && tv == 2);
            unsigned long long m3 = __ballot(valid && tv == 3);
            if (lane == 0) {
                rowsm[r][0] = m0; rowsm[r][1] = m1;
                rowsm[r][2] = m2; rowsm[r][3] = m3;
            }
        }
    }
    __syncthreads();

    // ---- pre-OR +-dy pairs: two u64 per thread ----
    #pragma unroll
    for (int q = 0; q < 2; ++q) {
        int idx = tid + 256 * q;            // 0..511
        int yy = idx >> 4, c = (idx >> 2) & 3, lvl = idx & 3;
        unsigned long long v = (lvl == 0)
            ? rowsm[16 + yy][c]
            : (rowsm[16 + yy - lvl][c] | rowsm[16 + yy + lvl][c]);
        big[yy * 18 + c * 4 + lvl] = v;
    }
    __syncthreads();

    // ---- per-pixel fused loss: 4 consecutive-x pixels per thread ----
    int xq = (tid & 7) * 4;                 // 0,4,...,28
    int y = tid >> 3;                       // 0..31
    int ya = y0 + y, ly = y + 16;

    float red[9];
    #pragma unroll
    for (int j = 0; j < 9; ++j) red[j] = 0.0f;

    // softmax probabilities for the 4 pixels (float4 per class)
    float pr[4][4];                         // [class][pixel]
    {
        const float* ob = outputs + (size_t)b * CHW + (size_t)ya * W + (x0 + xq);
        float4 f[4];
        f[0] = *(const float4*)ob;
        f[1] = *(const float4*)(ob + HW);
        f[2] = *(const float4*)(ob + 2 * HW);
        f[3] = *(const float4*)(ob + 3 * HW);
        #pragma unroll
        for (int c = 0; c < 4; ++c) {
            const float* fc = (const float*)&f[c];
            #pragma unroll
            for (int p = 0; p < 4; ++p) pr[c][p] = exp2f(fc[p] * LOG2E);
        }
        #pragma unroll
        for (int p = 0; p < 4; ++p) {
            float inv = 1.0f / (pr[0][p] + pr[1][p] + pr[2][p] + pr[3][p]);
            #pragma unroll
            for (int c = 0; c < 4; ++c) pr[c][p] *= inv;
        }
    }

    #pragma unroll
    for (int c = 0; c < 4; ++c) {
        const ulonglong2* pp = (const ulonglong2*)&big[y * 18 + c * 4];
        ulonglong2 va = pp[0], vb = pp[1];
        unsigned long long r0 = va.x >> xq;     // dy = 0   (bit 16+p = pixel p)
        unsigned long long r1 = va.y >> xq;     // |dy| = 1
        unsigned long long r2 = vb.x >> xq;     // |dy| = 2
        unsigned long long r3 = vb.y >> xq;     // |dy| = 3
        unsigned int l0 = (unsigned int)r0, l1 = (unsigned int)r1;
        unsigned int l2 = (unsigned int)r2, l3 = (unsigned int)r3;
        #pragma unroll
        for (int p = 0; p < 4; ++p) {
            unsigned int w0r = (unsigned int)(r0 >> (16 + p));
            unsigned int w1r = (unsigned int)(r1 >> (16 + p));
            unsigned int w2r = (unsigned int)(r2 >> (16 + p));
            unsigned int w3r = (unsigned int)(r3 >> (16 + p));
            unsigned int w0l = l0 << (15 - p);
            unsigned int w1l = l1 << (15 - p);
            unsigned int w2l = l2 << (15 - p);
            unsigned int w3l = l3 << (15 - p);
            int best = scan32(w0r, w0l, 0);
            best = min(best, scan32(w1r, w1l, 1));
            best = min(best, scan32(w2r, w2l, 4));
            best = min(best, scan32(w3r, w3l, 9));
            if (best > 16) {                    // rare: exact extension
                int lx = 16 + xq + p, shl = 63 - lx;
                for (int dy = 4; dy <= 16 && dy * dy < best; ++dy) {
                    unsigned long long mm = rowsm[ly + dy][c] | rowsm[ly - dy][c];
                    if (mm) best = min(best, dy * dy + nearest2(mm, lx, shl));
                }
                if (best > 289) {
                    best = min(best, BIG2);
                    best = ring_fallback(tg, x0 + xq + p, ya, c, best);
                }
            }
            float dt = sqrtf((float)best);      // exact int < 2^24
            red[0] += pr[c][p] * dt;            // target class: dt==0
            if (w0r & 1u) red[1 + c] += pr[c][p];   // T contribution
            red[5 + c] = fmaxf(red[5 + c], dt); // slice max candidate
        }
    }

    // ---- block reduce: red[0..4] sum, red[5..8] max ----
    #pragma unroll
    for (int off = 32; off > 0; off >>= 1) {
        #pragma unroll
        for (int j = 0; j < 5; ++j) red[j] += __shfl_down(red[j], off);
        #pragma unroll
        for (int j = 5; j < 9; ++j) red[j] = fmaxf(red[j], __shfl_down(red[j], off));
    }
    if (lane == 0) {
        #pragma unroll
        for (int j = 0; j < 9; ++j) sred[wv][j] = red[j];
    }
    __syncthreads();
    if (tid == 0) {
        float o[9];
        #pragma unroll
        for (int j = 0; j < 9; ++j) o[j] = sred[0][j];
        #pragma unroll
        for (int w = 1; w < 4; ++w) {
            #pragma unroll
            for (int j = 0; j < 5; ++j) o[j] += sred[w][j];
            #pragma unroll
            for (int j = 5; j < 9; ++j) o[j] = fmaxf(o[j], sred[w][j]);
        }
        // SoA: plane j is contiguous over blocks -> coalesced finalize reads
        #pragma unroll
        for (int j = 0; j < 9; ++j) parts[j * NBLK + bid] = o[j];
    }
}

// Single block: reduce 1152 block partials (SoA planes) -> scalar loss.
__global__ __launch_bounds__(256)
void finalize(const float* __restrict__ parts, float* __restrict__ out) {
    __shared__ double asum[4];
    __shared__ double Tsh[32];
    __shared__ float Msh[32];
    int tid = threadIdx.x, lane = tid & 63, wv = tid >> 6;

    double a = 0.0;
    for (int i = tid; i < NBLK; i += 256) a += (double)parts[i];   // plane 0
    #pragma unroll
    for (int off = 32; off > 0; off >>= 1) a += __shfl_down(a, off);
    if (lane == 0) asum[wv] = a;

    for (int k = 0; k < 8; ++k) {
        int s = wv * 8 + k;
        int b = s >> 2, c = s & 3;
        double ts = 0.0;
        float ms = 0.0f;
        for (int i = lane; i < TPI; i += 64) {
            int blk = b * TPI + i;
            ts += (double)parts[(1 + c) * NBLK + blk];     // coalesced
            ms = fmaxf(ms, parts[(5 + c) * NBLK + blk]);   // coalesced
        }
        #pragma unroll
        for (int off = 32; off > 0; off >>= 1) {
            ts += __shfl_down(ts, off);
            ms = fmaxf(ms, __shfl_down(ms, off));
        }
        if (lane == 0) { Tsh[s] = ts; Msh[s] = ms; }
    }
    __syncthreads();
    if (tid == 0) {
        double A = asum[0] + asum[1] + asum[2] + asum[3];
        double st = 0.0;
        for (int s = 0; s < 32; ++s) st += (double)Msh[s] * Tsh[s];
        out[0] = (float)((A - st) / ((double)C * (double)NTOT));
    }
}

extern "C" void kernel_launch(void* const* d_in, const int* in_sizes, int n_in,
                              void* d_out, int out_size, void* d_ws, size_t ws_size,
                              hipStream_t stream) {
    const float* outputs = (const float*)d_in[0];
    const int* targets = (const int*)d_in[1];
    float* out = (float*)d_out;
    float* parts = (float*)d_ws;   // 9 planes x NBLK floats = 41.5 KB (SoA)

    dist_loss_kernel<<<NBLK, 256, 0, stream>>>(outputs, targets, parts);
    finalize<<<1, 256, 0, stream>>>(parts, out);
}